// Round 2
// baseline (880.967 us; speedup 1.0000x reference)
//
#include <hip/hip_runtime.h>
#include <hip/hip_bf16.h>

// Shapes: B=32, T=512, F=32, D=256.  M = B*T = 16384.
#define M_TOT 16384
#define F_N 32
#define D_N 256

typedef float f32x4 __attribute__((ext_vector_type(4)));
typedef short s16x8 __attribute__((ext_vector_type(8)));

__device__ __forceinline__ f32x4 mfma_bf16(s16x8 a, s16x8 b, f32x4 c) {
  asm("v_mfma_f32_16x16x32_bf16 %0, %1, %2, %0" : "+v"(c) : "v"(a), "v"(b));
  return c;
}

__device__ __forceinline__ short f2bf(float x) {
  __hip_bfloat16 h = __float2bfloat16(x);
  unsigned short u;
  __builtin_memcpy(&u, &h, 2);
  return (short)u;
}

__device__ __forceinline__ float eluf(float z) {
  return z > 0.f ? z : (__expf(z) - 1.f);
}
__device__ __forceinline__ float sigm(float z) {
  return 1.f / (1.f + __expf(-z));
}

// ---------------------------------------------------------------------------
// Kernel 0: pack f_w2 / f_wp / f_wg (fp32 [32][256][256], d-major) into bf16
// MFMA-B fragment order (one coalesced dwordx4 per lane per fragment).
// ---------------------------------------------------------------------------
__global__ __launch_bounds__(256) void pack_weights(
    const float* __restrict__ w2, const float* __restrict__ wp,
    const float* __restrict__ wg, s16x8* __restrict__ pbo) {
  int t = blockIdx.x * 256 + threadIdx.x;
  int l   = t & 63;
  int n16 = (t >> 6) & 15;
  int ks  = (t >> 10) & 7;
  int f   = (t >> 13) & 31;
  int mat = t >> 18;
  const float* src = (mat == 0) ? w2 : ((mat == 1) ? wp : wg);
  int d0 = ks * 32 + ((l >> 4) << 3);
  int e  = n16 * 16 + (l & 15);
  const float* p = src + ((size_t)f * D_N + d0) * D_N + e;
  s16x8 v;
#pragma unroll
  for (int j = 0; j < 8; ++j) v[j] = f2bf(p[(size_t)j * D_N]);
  pbo[t] = v;
}

// ---------------------------------------------------------------------------
// Kernel 1: weight GRN over F=32 + softmax (fp32 exact). One row per thread.
// ---------------------------------------------------------------------------
__global__ __launch_bounds__(128) void vsn_weights(
    const float* __restrict__ x,
    const float* __restrict__ g_w1, const float* __restrict__ g_b1,
    const float* __restrict__ g_w2, const float* __restrict__ g_b2,
    const float* __restrict__ g_wp, const float* __restrict__ g_bp,
    const float* __restrict__ g_wg, const float* __restrict__ g_bg,
    const float* __restrict__ g_gamma, const float* __restrict__ g_beta,
    const float* __restrict__ p_w, const float* __restrict__ p_b,
    float* __restrict__ w_out) {
  __shared__ float xs[128][33];
  __shared__ float Wm[5][32][32];
  __shared__ float Bv[7][32];
  const int tid = threadIdx.x;
  const long m0 = (long)blockIdx.x * 128;

  for (int i = tid; i < 128 * 32; i += 128) xs[i >> 5][i & 31] = x[m0 * 32 + i];
  for (int i = tid; i < 1024; i += 128) {
    int r = i >> 5, c = i & 31;
    Wm[0][r][c] = g_w1[i];
    Wm[1][r][c] = g_w2[i];
    Wm[2][r][c] = g_wp[i];
    Wm[3][r][c] = g_wg[i];
    Wm[4][r][c] = p_w[i];
  }
  if (tid < 32) {
    Bv[0][tid] = g_b1[tid];
    Bv[1][tid] = g_b2[tid];
    Bv[2][tid] = g_bp[tid];
    Bv[3][tid] = g_bg[tid];
    Bv[4][tid] = g_gamma[tid];
    Bv[5][tid] = g_beta[tid];
    Bv[6][tid] = p_b[tid];
  }
  __syncthreads();

  float h[32], u[32];
#pragma unroll
  for (int i = 0; i < 32; ++i) {
    float s = Bv[0][i];
#pragma unroll
    for (int j = 0; j < 32; ++j) s += xs[tid][j] * Wm[0][j][i];
    h[i] = eluf(s);
  }
#pragma unroll
  for (int i = 0; i < 32; ++i) {
    float s = Bv[1][i];
#pragma unroll
    for (int j = 0; j < 32; ++j) s += h[j] * Wm[1][j][i];
    u[i] = s;
  }
#pragma unroll
  for (int i = 0; i < 32; ++i) {
    float sp = Bv[2][i], sg = Bv[3][i];
#pragma unroll
    for (int j = 0; j < 32; ++j) {
      sp += u[j] * Wm[2][j][i];
      sg += u[j] * Wm[3][j][i];
    }
    h[i] = sp * sigm(sg) + xs[tid][i];
  }
  float ss = 0.f;
#pragma unroll
  for (int i = 0; i < 32; ++i) ss += h[i];
  float mean = ss * (1.f / 32.f);
  float sq = 0.f;
#pragma unroll
  for (int i = 0; i < 32; ++i) {
    float d = h[i] - mean;
    sq += d * d;
  }
  float rstd = rsqrtf(sq * (1.f / 32.f) + 1e-5f);
#pragma unroll
  for (int i = 0; i < 32; ++i) u[i] = (h[i] - mean) * rstd * Bv[4][i] + Bv[5][i];
#pragma unroll
  for (int i = 0; i < 32; ++i) {
    float s = Bv[6][i];
#pragma unroll
    for (int j = 0; j < 32; ++j) s += u[j] * Wm[4][j][i];
    h[i] = s;
  }
  float mx = h[0];
#pragma unroll
  for (int i = 1; i < 32; ++i) mx = fmaxf(mx, h[i]);
  float se = 0.f;
#pragma unroll
  for (int i = 0; i < 32; ++i) {
    h[i] = __expf(h[i] - mx);
    se += h[i];
  }
  float inv = 1.f / se;
#pragma unroll
  for (int i = 0; i < 32; ++i) w_out[(m0 + tid) * 32 + i] = h[i] * inv;
}

// ---------------------------------------------------------------------------
// Kernel 2: fused per-feature GRNs + LN + weighted selection.
// 512 blocks x 256 threads (4 waves, 1m x 4n). Block = 32 rows.
// Software-pipelined over f: per-f barriers reduced 4 -> 2;
//   segA: phase2 MFMA (h1[cur]) || phase4-finish(f-1) ; h2 epilogue ; sync
//   segB: phase3 MFMA (h2) || phase1(f+1 -> h1[cur^1]) ; phase4-pre ; sync
// LDS 57 KB -> 2 independent blocks per CU overlap each other's barriers.
// ---------------------------------------------------------------------------
__global__ __launch_bounds__(256, 2) void vsn_main(
    const float* __restrict__ x, const float* __restrict__ f_w1,
    const float* __restrict__ f_b1, const float* __restrict__ f_b2,
    const float* __restrict__ f_bp, const float* __restrict__ f_bg,
    const float* __restrict__ f_ws, const float* __restrict__ f_bs,
    const float* __restrict__ f_gamma, const float* __restrict__ f_beta,
    const float* __restrict__ wts, const s16x8* __restrict__ pb,
    float* __restrict__ out) {
  __shared__ __align__(16) short h1s[2][32 * 256];  // 32 KB dbuf, swizzled
  __shared__ __align__(16) short h2s[32 * 256];     // 16 KB, swizzled
  __shared__ float xt[32 * 32];                     // 4 KB
  __shared__ float wt[32 * 32];                     // 4 KB
  __shared__ float red[32 * 4 * 2];                 // 1 KB  LN partials

  const int tid  = threadIdx.x;
  const int lane = tid & 63;
  const int wn   = tid >> 6;  // 0..3 : 64-col strip
  const int l15  = lane & 15;
  const int l4   = lane >> 4;
  const long m0  = (long)blockIdx.x * 32;

  for (int i = tid; i < 32 * 32; i += 256) {
    xt[i] = x[m0 * 32 + i];
    wt[i] = wts[m0 * 32 + i];
  }

  f32x4 acc[2][4];
#pragma unroll
  for (int a = 0; a < 2; ++a)
#pragma unroll
    for (int b = 0; b < 4; ++b) acc[a][b] = (f32x4){0.f, 0.f, 0.f, 0.f};

  // ---- phase 1 for feature fp -> h1s[buf] ----
  auto phase1 = [&](int fp, int buf) {
    short* h1b = &h1s[buf][0];
#pragma unroll
    for (int it = 0; it < 4; ++it) {
      int idx = tid + it * 256;  // 0..1023
      int row = idx >> 5;
      int db  = idx & 31;
      float xm = xt[row * 32 + fp];
      f32x4 w1a = *(const f32x4*)(f_w1 + fp * 256 + db * 8);
      f32x4 w1b = *(const f32x4*)(f_w1 + fp * 256 + db * 8 + 4);
      f32x4 b1a = *(const f32x4*)(f_b1 + fp * 256 + db * 8);
      f32x4 b1b = *(const f32x4*)(f_b1 + fp * 256 + db * 8 + 4);
      s16x8 v;
#pragma unroll
      for (int j = 0; j < 4; ++j) v[j] = f2bf(eluf(xm * w1a[j] + b1a[j]));
#pragma unroll
      for (int j = 0; j < 4; ++j) v[4 + j] = f2bf(eluf(xm * w1b[j] + b1b[j]));
      *(s16x8*)((char*)h1b + row * 512 + ((db * 16) ^ ((row & 7) << 4))) = v;
    }
  };

  float pv[2][4][4];     // stacked pre-LN values for feature f (segB -> segA)
  float gamP[4], betP[4];

  // ---- phase-4 finish for feature fp (uses red + pv + gamP/betP) ----
  auto finish = [&](int fp) {
#pragma unroll
    for (int mf = 0; mf < 2; ++mf) {
#pragma unroll
      for (int r = 0; r < 4; ++r) {
        int row = mf * 16 + l4 * 4 + r;
        float ss = 0.f, sq = 0.f;
#pragma unroll
        for (int w = 0; w < 4; ++w) {
          ss += red[(row * 4 + w) * 2];
          sq += red[(row * 4 + w) * 2 + 1];
        }
        float mean = ss * (1.f / 256.f);
        float var  = sq * (1.f / 256.f) - mean * mean;
        float rstd = rsqrtf(var + 1e-5f);
        float wrow = wt[row * 32 + fp];
#pragma unroll
        for (int nf = 0; nf < 4; ++nf)
          acc[mf][nf][r] += wrow * ((pv[mf][nf][r] - mean) * rstd * gamP[nf] + betP[nf]);
      }
    }
  };

  __syncthreads();   // xt/wt visible
  phase1(0, 0);
  __syncthreads();   // h1s[0] visible

  for (int f = 0; f < F_N; ++f) {
    const int cur = f & 1;
    // ================= segment A =================
    // phase 2: h2 = h1 @ W2  (MFMA) ; finish(f-1) fills MFMA latency
    f32x4 a2[2][4];
#pragma unroll
    for (int a = 0; a < 2; ++a)
#pragma unroll
      for (int b = 0; b < 4; ++b) a2[a][b] = (f32x4){0.f, 0.f, 0.f, 0.f};
    const s16x8* pb2 = pb + (size_t)f * 8192;
    const short* h1b = &h1s[cur][0];
#pragma unroll 4
    for (int ks = 0; ks < 8; ++ks) {
      s16x8 afr[2];
#pragma unroll
      for (int mf = 0; mf < 2; ++mf) {
        int row = mf * 16 + l15;
        int kb  = ks * 64 + l4 * 16;
        afr[mf] = *(const s16x8*)((const char*)h1b + row * 512 + (kb ^ ((row & 7) << 4)));
      }
#pragma unroll
      for (int nf = 0; nf < 4; ++nf) {
        s16x8 bfr = pb2[(ks * 16 + wn * 4 + nf) * 64 + lane];
#pragma unroll
        for (int mf = 0; mf < 2; ++mf) a2[mf][nf] = mfma_bf16(afr[mf], bfr, a2[mf][nf]);
      }
    }
    if (f > 0) finish(f - 1);
    // epilogue: +b2, cast bf16, store to h2s (swizzled)
#pragma unroll
    for (int nf = 0; nf < 4; ++nf) {
      int col = wn * 64 + nf * 16 + l15;
      float b2v = f_b2[f * 256 + col];
#pragma unroll
      for (int mf = 0; mf < 2; ++mf) {
        int row0 = mf * 16 + l4 * 4;
#pragma unroll
        for (int r = 0; r < 4; ++r) {
          int row = row0 + r;
          *(short*)((char*)h2s + row * 512 + ((col * 2) ^ ((row & 7) << 4))) =
              f2bf(a2[mf][nf][r] + b2v);
        }
      }
    }
    __syncthreads();  // h2s visible; h1s[cur^1] (written last segB) already synced

    // ================= segment B =================
    // phase 3: p = h2 @ Wp, g = h2 @ Wg ; phase1(f+1) overlaps MFMA
    f32x4 ap[2][4], ag[2][4];
#pragma unroll
    for (int a = 0; a < 2; ++a)
#pragma unroll
      for (int b = 0; b < 4; ++b) {
        ap[a][b] = (f32x4){0.f, 0.f, 0.f, 0.f};
        ag[a][b] = (f32x4){0.f, 0.f, 0.f, 0.f};
      }
    const s16x8* pbp = pb + (size_t)(32 + f) * 8192;
    const s16x8* pbg = pb + (size_t)(64 + f) * 8192;
#pragma unroll 4
    for (int ks = 0; ks < 8; ++ks) {
      s16x8 afr[2];
#pragma unroll
      for (int mf = 0; mf < 2; ++mf) {
        int row = mf * 16 + l15;
        int kb  = ks * 64 + l4 * 16;
        afr[mf] = *(const s16x8*)((const char*)h2s + row * 512 + (kb ^ ((row & 7) << 4)));
      }
#pragma unroll
      for (int nf = 0; nf < 4; ++nf) {
        s16x8 bp_ = pbp[(ks * 16 + wn * 4 + nf) * 64 + lane];
        s16x8 bg_ = pbg[(ks * 16 + wn * 4 + nf) * 64 + lane];
#pragma unroll
        for (int mf = 0; mf < 2; ++mf) {
          ap[mf][nf] = mfma_bf16(afr[mf], bp_, ap[mf][nf]);
          ag[mf][nf] = mfma_bf16(afr[mf], bg_, ag[mf][nf]);
        }
      }
    }
    if (f + 1 < F_N) phase1(f + 1, cur ^ 1);

    // phase 4 (pre): GLU + residual -> pv ; partial LN sums -> red
    float bpv[4], bgv[4], wsv[4], bsv[4];
#pragma unroll
    for (int nf = 0; nf < 4; ++nf) {
      int col = wn * 64 + nf * 16 + l15;
      bpv[nf]  = f_bp[f * 256 + col];
      bgv[nf]  = f_bg[f * 256 + col];
      gamP[nf] = f_gamma[f * 256 + col];
      betP[nf] = f_beta[f * 256 + col];
      wsv[nf]  = f_ws[f * 256 + col];
      bsv[nf]  = f_bs[f * 256 + col];
    }
    float s1[2][4], s2[2][4];
#pragma unroll
    for (int mf = 0; mf < 2; ++mf) {
#pragma unroll
      for (int r = 0; r < 4; ++r) {
        int row = mf * 16 + l4 * 4 + r;
        float xm = xt[row * 32 + f];
        float ss = 0.f, sq = 0.f;
#pragma unroll
        for (int nf = 0; nf < 4; ++nf) {
          float pvv = ap[mf][nf][r] + bpv[nf];
          float gv  = ag[mf][nf][r] + bgv[nf];
          float val = pvv * sigm(gv) + (xm * wsv[nf] + bsv[nf]);
          pv[mf][nf][r] = val;
          ss += val;
          sq += val * val;
        }
        s1[mf][r] = ss;
        s2[mf][r] = sq;
      }
    }
#pragma unroll
    for (int mf = 0; mf < 2; ++mf)
#pragma unroll
      for (int r = 0; r < 4; ++r) {
#pragma unroll
        for (int m = 1; m <= 8; m <<= 1) {
          s1[mf][r] += __shfl_xor(s1[mf][r], m);
          s2[mf][r] += __shfl_xor(s2[mf][r], m);
        }
      }
    if (l15 == 0) {
#pragma unroll
      for (int mf = 0; mf < 2; ++mf)
#pragma unroll
        for (int r = 0; r < 4; ++r) {
          int row = mf * 16 + l4 * 4 + r;
          red[(row * 4 + wn) * 2]     = s1[mf][r];
          red[(row * 4 + wn) * 2 + 1] = s2[mf][r];
        }
    }
    __syncthreads();  // red visible; h1s[cur^1] visible for next segA
  }

  finish(F_N - 1);

  // ---- store selected ----
#pragma unroll
  for (int mf = 0; mf < 2; ++mf)
#pragma unroll
    for (int r = 0; r < 4; ++r) {
      long row = m0 + mf * 16 + l4 * 4 + r;
#pragma unroll
      for (int nf = 0; nf < 4; ++nf)
        out[row * 256 + wn * 64 + nf * 16 + l15] = acc[mf][nf][r];
    }
}

// ---------------------------------------------------------------------------
extern "C" void kernel_launch(void* const* d_in, const int* in_sizes, int n_in,
                              void* d_out, int out_size, void* d_ws, size_t ws_size,
                              hipStream_t stream) {
  const float* x       = (const float*)d_in[0];
  const float* f_w1    = (const float*)d_in[1];
  const float* f_b1    = (const float*)d_in[2];
  const float* f_w2    = (const float*)d_in[3];
  const float* f_b2    = (const float*)d_in[4];
  const float* f_wp    = (const float*)d_in[5];
  const float* f_bp    = (const float*)d_in[6];
  const float* f_wg    = (const float*)d_in[7];
  const float* f_bg    = (const float*)d_in[8];
  const float* f_ws    = (const float*)d_in[9];
  const float* f_bs    = (const float*)d_in[10];
  const float* f_gamma = (const float*)d_in[11];
  const float* f_beta  = (const float*)d_in[12];
  const float* g_w1    = (const float*)d_in[13];
  const float* g_b1    = (const float*)d_in[14];
  const float* g_w2    = (const float*)d_in[15];
  const float* g_b2    = (const float*)d_in[16];
  const float* g_wp    = (const float*)d_in[17];
  const float* g_bp    = (const float*)d_in[18];
  const float* g_wg    = (const float*)d_in[19];
  const float* g_bg    = (const float*)d_in[20];
  const float* g_gamma = (const float*)d_in[21];
  const float* g_beta  = (const float*)d_in[22];
  const float* p_w     = (const float*)d_in[23];
  const float* p_b     = (const float*)d_in[24];

  float* out_sel = (float*)d_out;                  // [16384, 256]
  float* out_w   = out_sel + (size_t)M_TOT * D_N;  // [16384, 32]
  s16x8* pbw     = (s16x8*)d_ws;                   // 12.6 MB packed bf16

  pack_weights<<<3072, 256, 0, stream>>>(f_w2, f_wp, f_wg, pbw);
  vsn_weights<<<128, 128, 0, stream>>>(x, g_w1, g_b1, g_w2, g_b2, g_wp, g_bp,
                                       g_wg, g_bg, g_gamma, g_beta, p_w, p_b,
                                       out_w);
  vsn_main<<<512, 256, 0, stream>>>(x, f_w1, f_b1, f_b2, f_bp, f_bg, f_ws,
                                    f_bs, f_gamma, f_beta, out_w,
                                    (const s16x8*)d_ws, out_sel);
}

// Round 3
// 428.779 us; speedup vs baseline: 2.0546x; 2.0546x over previous
//
#include <hip/hip_runtime.h>
#include <hip/hip_bf16.h>

// Shapes: B=32, T=512, F=32, D=256.  M = B*T = 16384.
#define M_TOT 16384
#define F_N 32
#define D_N 256

typedef float f32x4 __attribute__((ext_vector_type(4)));
typedef float f32x2 __attribute__((ext_vector_type(2)));
typedef short s16x8 __attribute__((ext_vector_type(8)));

__device__ __forceinline__ f32x4 mfma_bf16(s16x8 a, s16x8 b, f32x4 c) {
  asm("v_mfma_f32_16x16x32_bf16 %0, %1, %2, %0" : "+v"(c) : "v"(a), "v"(b));
  return c;
}
__device__ __forceinline__ short f2bf(float x) {
  __hip_bfloat16 h = __float2bfloat16(x);
  unsigned short u;
  __builtin_memcpy(&u, &h, 2);
  return (short)u;
}
__device__ __forceinline__ float eluf(float z) {
  return z > 0.f ? z : (__expf(z) - 1.f);
}
__device__ __forceinline__ float sigm(float z) {
  return 1.f / (1.f + __expf(-z));
}

// ---------------------------------------------------------------------------
// Kernel 0a: Wp' = W2 @ Wp, Wg' = W2 @ Wg per feature (fp32 accum), packed
// straight into bf16 MFMA-B fragment order.
// grid: (mat*32 + f)*8 + kstrip ; block 256 thr = one output column each.
// A-row values are wave-uniform -> compiler scalarizes to s_load.
// ---------------------------------------------------------------------------
__global__ __launch_bounds__(256) void pack_wprime(
    const float* __restrict__ w2, const float* __restrict__ wp,
    const float* __restrict__ wg, s16x8* __restrict__ pbo) {
  int bid = blockIdx.x;
  int s   = bid & 7;          // k-strip: rows s*32..s*32+31 of W'
  int f   = (bid >> 3) & 31;
  int mat = bid >> 8;         // 0 = Wp', 1 = Wg'
  const float* A  = w2 + (size_t)f * 65536 + (size_t)s * 32 * 256;
  const float* Bm = (mat ? wg : wp) + (size_t)f * 65536;
  const int e = threadIdx.x;  // output column

  float acc[32];
#pragma unroll
  for (int r = 0; r < 32; ++r) acc[r] = 0.f;

  for (int d = 0; d < 256; d += 4) {
    float bv0 = Bm[(size_t)(d + 0) * 256 + e];
    float bv1 = Bm[(size_t)(d + 1) * 256 + e];
    float bv2 = Bm[(size_t)(d + 2) * 256 + e];
    float bv3 = Bm[(size_t)(d + 3) * 256 + e];
#pragma unroll
    for (int r = 0; r < 32; ++r) {
      f32x4 a4 = *(const f32x4*)(A + r * 256 + d);  // uniform -> s_load
      acc[r] += a4[0] * bv0;
      acc[r] += a4[1] * bv1;
      acc[r] += a4[2] * bv2;
      acc[r] += a4[3] * bv3;
    }
  }
  // pack into PB[(mat*32+f)][ks=s][n16=e>>4][lane=l4*16+(e&15)][j]
  s16x8* dst = pbo + (size_t)(mat * 32 + f) * 8192 + (s * 16 + (e >> 4)) * 64 + (e & 15);
#pragma unroll
  for (int l4 = 0; l4 < 4; ++l4) {
    s16x8 v;
#pragma unroll
    for (int j = 0; j < 8; ++j) v[j] = f2bf(acc[l4 * 8 + j]);
    dst[l4 * 16] = v;
  }
}

// ---------------------------------------------------------------------------
// Kernel 0b: bp' = b2 @ Wp + bp ; bg' = b2 @ Wg + bg  (fp32)
// ---------------------------------------------------------------------------
__global__ __launch_bounds__(256) void pack_bias(
    const float* __restrict__ b2, const float* __restrict__ wp,
    const float* __restrict__ wg, const float* __restrict__ bp,
    const float* __restrict__ bg, float* __restrict__ bias_o) {
  int bid = blockIdx.x;  // mat*32 + f
  int f = bid & 31, mat = bid >> 5;
  const float* Bm  = (mat ? wg : wp) + (size_t)f * 65536;
  const float* bb  = (mat ? bg : bp) + f * 256;
  const float* b2f = b2 + f * 256;
  int e = threadIdx.x;
  float s = bb[e];
  for (int d = 0; d < 256; ++d) s += b2f[d] * Bm[(size_t)d * 256 + e];  // b2f[d] uniform
  bias_o[bid * 256 + e] = s;
}

// ---------------------------------------------------------------------------
// Kernel 1: weight GRN over F=32 + softmax (fp32 exact). One row per thread.
// ---------------------------------------------------------------------------
__global__ __launch_bounds__(64) void vsn_weights(
    const float* __restrict__ x,
    const float* __restrict__ g_w1, const float* __restrict__ g_b1,
    const float* __restrict__ g_w2, const float* __restrict__ g_b2,
    const float* __restrict__ g_wp, const float* __restrict__ g_bp,
    const float* __restrict__ g_wg, const float* __restrict__ g_bg,
    const float* __restrict__ g_gamma, const float* __restrict__ g_beta,
    const float* __restrict__ p_w, const float* __restrict__ p_b,
    float* __restrict__ w_out) {
  __shared__ float xs[64][33];
  __shared__ float Wm[5][32][32];
  __shared__ float Bv[7][32];
  const int tid = threadIdx.x;
  const long m0 = (long)blockIdx.x * 64;

  for (int i = tid; i < 64 * 32; i += 64) xs[i >> 5][i & 31] = x[m0 * 32 + i];
  for (int i = tid; i < 1024; i += 64) {
    int r = i >> 5, c = i & 31;
    Wm[0][r][c] = g_w1[i];
    Wm[1][r][c] = g_w2[i];
    Wm[2][r][c] = g_wp[i];
    Wm[3][r][c] = g_wg[i];
    Wm[4][r][c] = p_w[i];
  }
  if (tid < 32) {
    Bv[0][tid] = g_b1[tid];
    Bv[1][tid] = g_b2[tid];
    Bv[2][tid] = g_bp[tid];
    Bv[3][tid] = g_bg[tid];
    Bv[4][tid] = g_gamma[tid];
    Bv[5][tid] = g_beta[tid];
    Bv[6][tid] = p_b[tid];
  }
  __syncthreads();

  float h[32], u[32];
#pragma unroll
  for (int i = 0; i < 32; ++i) {
    float s = Bv[0][i];
#pragma unroll
    for (int j = 0; j < 32; ++j) s += xs[tid][j] * Wm[0][j][i];
    h[i] = eluf(s);
  }
#pragma unroll
  for (int i = 0; i < 32; ++i) {
    float s = Bv[1][i];
#pragma unroll
    for (int j = 0; j < 32; ++j) s += h[j] * Wm[1][j][i];
    u[i] = s;
  }
#pragma unroll
  for (int i = 0; i < 32; ++i) {
    float sp = Bv[2][i], sg = Bv[3][i];
#pragma unroll
    for (int j = 0; j < 32; ++j) {
      sp += u[j] * Wm[2][j][i];
      sg += u[j] * Wm[3][j][i];
    }
    h[i] = sp * sigm(sg) + xs[tid][i];
  }
  float ss = 0.f;
#pragma unroll
  for (int i = 0; i < 32; ++i) ss += h[i];
  float mean = ss * (1.f / 32.f);
  float sq = 0.f;
#pragma unroll
  for (int i = 0; i < 32; ++i) {
    float d = h[i] - mean;
    sq += d * d;
  }
  float rstd = rsqrtf(sq * (1.f / 32.f) + 1e-5f);
#pragma unroll
  for (int i = 0; i < 32; ++i) u[i] = (h[i] - mean) * rstd * Bv[4][i] + Bv[5][i];
#pragma unroll
  for (int i = 0; i < 32; ++i) {
    float s = Bv[6][i];
#pragma unroll
    for (int j = 0; j < 32; ++j) s += u[j] * Wm[4][j][i];
    h[i] = s;
  }
  float mx = h[0];
#pragma unroll
  for (int i = 1; i < 32; ++i) mx = fmaxf(mx, h[i]);
  float se = 0.f;
#pragma unroll
  for (int i = 0; i < 32; ++i) {
    h[i] = __expf(h[i] - mx);
    se += h[i];
  }
  float inv = 1.f / se;
#pragma unroll
  for (int i = 0; i < 32; ++i) w_out[(m0 + tid) * 32 + i] = h[i] * inv;
}

// ---------------------------------------------------------------------------
// Kernel 2: fused per-feature GRNs (phase-2 GEMM folded into Wp'/Wg') + LN +
// weighted selection. 256 blocks x 512 thr (8 waves, 2m x 4n). 64-row tile.
// ONE barrier per feature:
//   { GEMM(p,g) from h1s[cur] || phase1(f+1)->h1s[cur^1] || phase4-pre }
//   barrier ; finish(f)
// h1 and red are ping-pong buffered -> race-free with a single barrier.
// ---------------------------------------------------------------------------
__global__ __launch_bounds__(512, 2) void vsn_main(
    const float* __restrict__ x, const float* __restrict__ f_w1,
    const float* __restrict__ f_b1,
    const float* __restrict__ f_ws, const float* __restrict__ f_bs,
    const float* __restrict__ f_gamma, const float* __restrict__ f_beta,
    const float* __restrict__ wts, const s16x8* __restrict__ pb,
    const float* __restrict__ pbias, float* __restrict__ out) {
  __shared__ __align__(16) short h1s[2][64 * 256];  // 64 KB dbuf, XOR-swizzled
  __shared__ float xtT[32 * 65];                    // x transposed [f][row], pad 65
  __shared__ float wtT[32 * 65];                    // weights transposed
  __shared__ __align__(16) f32x2 red[2][64][4];     // LN partials ping-pong

  const int tid  = threadIdx.x;
  const int lane = tid & 63;
  const int wv   = tid >> 6;  // 0..7
  const int wm   = wv >> 2;   // 0..1 : 32-row half
  const int wn   = wv & 3;    // 0..3 : 64-col strip
  const int l15  = lane & 15;
  const int l4   = lane >> 4;
  const long m0  = (long)blockIdx.x * 64;

  for (int i = tid; i < 64 * 32; i += 512) {
    float xv = x[m0 * 32 + i];
    float wv_ = wts[m0 * 32 + i];
    int ff = i & 31, row = i >> 5;
    xtT[ff * 65 + row] = xv;
    wtT[ff * 65 + row] = wv_;
  }

  f32x4 acc[2][4];
#pragma unroll
  for (int a = 0; a < 2; ++a)
#pragma unroll
    for (int b = 0; b < 4; ++b) acc[a][b] = (f32x4){0.f, 0.f, 0.f, 0.f};

  auto phase1 = [&](int fp, int buf) {
    short* h1b = &h1s[buf][0];
#pragma unroll
    for (int it = 0; it < 4; ++it) {
      int idx = tid + it * 512;  // 64 rows x 32 d-blocks
      int row = idx >> 5;
      int db  = idx & 31;
      float xm = xtT[fp * 65 + row];
      f32x4 w1a = *(const f32x4*)(f_w1 + fp * 256 + db * 8);
      f32x4 w1b = *(const f32x4*)(f_w1 + fp * 256 + db * 8 + 4);
      f32x4 b1a = *(const f32x4*)(f_b1 + fp * 256 + db * 8);
      f32x4 b1b = *(const f32x4*)(f_b1 + fp * 256 + db * 8 + 4);
      s16x8 v;
#pragma unroll
      for (int j = 0; j < 4; ++j) v[j] = f2bf(eluf(xm * w1a[j] + b1a[j]));
#pragma unroll
      for (int j = 0; j < 4; ++j) v[4 + j] = f2bf(eluf(xm * w1b[j] + b1b[j]));
      *(s16x8*)((char*)h1b + row * 512 + ((db * 16) ^ ((row & 7) << 4))) = v;
    }
  };

  __syncthreads();  // xtT/wtT visible
  phase1(0, 0);
  __syncthreads();  // h1s[0] visible

  for (int f = 0; f < F_N; ++f) {
    const int cur = f & 1;
    // ---- GEMM: p = h1 @ Wp' , g = h1 @ Wg'  (B-frags streamed from L2) ----
    f32x4 ap[2][4], ag[2][4];
#pragma unroll
    for (int a = 0; a < 2; ++a)
#pragma unroll
      for (int b = 0; b < 4; ++b) {
        ap[a][b] = (f32x4){0.f, 0.f, 0.f, 0.f};
        ag[a][b] = (f32x4){0.f, 0.f, 0.f, 0.f};
      }
    const s16x8* pbp = pb + (size_t)f * 8192;
    const s16x8* pbg = pb + (size_t)(32 + f) * 8192;
    const short* h1b = &h1s[cur][0];
#pragma unroll 2
    for (int ks = 0; ks < 8; ++ks) {
      s16x8 afr[2];
#pragma unroll
      for (int mf = 0; mf < 2; ++mf) {
        int row = wm * 32 + mf * 16 + l15;
        int kb  = ks * 64 + l4 * 16;
        afr[mf] = *(const s16x8*)((const char*)h1b + row * 512 + (kb ^ ((row & 7) << 4)));
      }
#pragma unroll
      for (int nf = 0; nf < 4; ++nf) {
        s16x8 bp_ = pbp[(ks * 16 + wn * 4 + nf) * 64 + lane];
        s16x8 bg_ = pbg[(ks * 16 + wn * 4 + nf) * 64 + lane];
#pragma unroll
        for (int mf = 0; mf < 2; ++mf) {
          ap[mf][nf] = mfma_bf16(afr[mf], bp_, ap[mf][nf]);
          ag[mf][nf] = mfma_bf16(afr[mf], bg_, ag[mf][nf]);
        }
      }
    }
    // ---- phase1 for next feature (independent VALU, fills MFMA shadow) ----
    if (f + 1 < F_N) phase1(f + 1, cur ^ 1);

    // ---- phase 4 (pre): GLU + residual -> pv ; LN partials -> red[cur] ----
    float bpv[4], bgv[4], gam[4], bet[4], wsv[4], bsv[4];
#pragma unroll
    for (int nf = 0; nf < 4; ++nf) {
      int col = wn * 64 + nf * 16 + l15;
      bpv[nf] = pbias[f * 256 + col];
      bgv[nf] = pbias[(32 + f) * 256 + col];
      gam[nf] = f_gamma[f * 256 + col];
      bet[nf] = f_beta[f * 256 + col];
      wsv[nf] = f_ws[f * 256 + col];
      bsv[nf] = f_bs[f * 256 + col];
    }
    float pv[2][4][4];
    float s1[2][4], s2[2][4];
#pragma unroll
    for (int mf = 0; mf < 2; ++mf) {
#pragma unroll
      for (int r = 0; r < 4; ++r) {
        int row = wm * 32 + mf * 16 + l4 * 4 + r;
        float xm = xtT[f * 65 + row];
        float ss = 0.f, sq = 0.f;
#pragma unroll
        for (int nf = 0; nf < 4; ++nf) {
          float pvv = ap[mf][nf][r] + bpv[nf];
          float gv  = ag[mf][nf][r] + bgv[nf];
          float val = pvv * sigm(gv) + (xm * wsv[nf] + bsv[nf]);
          pv[mf][nf][r] = val;
          ss += val;
          sq += val * val;
        }
        s1[mf][r] = ss;
        s2[mf][r] = sq;
      }
    }
#pragma unroll
    for (int mf = 0; mf < 2; ++mf)
#pragma unroll
      for (int r = 0; r < 4; ++r) {
#pragma unroll
        for (int m = 1; m <= 8; m <<= 1) {
          s1[mf][r] += __shfl_xor(s1[mf][r], m);
          s2[mf][r] += __shfl_xor(s2[mf][r], m);
        }
      }
    if (l15 == 0) {
#pragma unroll
      for (int mf = 0; mf < 2; ++mf)
#pragma unroll
        for (int r = 0; r < 4; ++r) {
          int row = wm * 32 + mf * 16 + l4 * 4 + r;
          red[cur][row][wn] = (f32x2){s1[mf][r], s2[mf][r]};
        }
    }
    __syncthreads();  // the ONE barrier: red[cur] + h1s[cur^1] visible

    // ---- finish: LN + weighted accumulate ----
#pragma unroll
    for (int mf = 0; mf < 2; ++mf) {
#pragma unroll
      for (int r = 0; r < 4; ++r) {
        int row = wm * 32 + mf * 16 + l4 * 4 + r;
        f32x4 q0 = *(const f32x4*)&red[cur][row][0];
        f32x4 q1 = *(const f32x4*)&red[cur][row][2];
        float ss = q0[0] + q0[2] + q1[0] + q1[2];
        float sq = q0[1] + q0[3] + q1[1] + q1[3];
        float mean = ss * (1.f / 256.f);
        float var  = sq * (1.f / 256.f) - mean * mean;
        float rstd = rsqrtf(var + 1e-5f);
        float wrow = wtT[f * 65 + row];
#pragma unroll
        for (int nf = 0; nf < 4; ++nf)
          acc[mf][nf][r] += wrow * ((pv[mf][nf][r] - mean) * rstd * gam[nf] + bet[nf]);
      }
    }
  }

  // ---- store selected ----
#pragma unroll
  for (int mf = 0; mf < 2; ++mf)
#pragma unroll
    for (int r = 0; r < 4; ++r) {
      long row = m0 + wm * 32 + mf * 16 + l4 * 4 + r;
#pragma unroll
      for (int nf = 0; nf < 4; ++nf)
        out[row * 256 + wn * 64 + nf * 16 + l15] = acc[mf][nf][r];
    }
}

// ---------------------------------------------------------------------------
extern "C" void kernel_launch(void* const* d_in, const int* in_sizes, int n_in,
                              void* d_out, int out_size, void* d_ws, size_t ws_size,
                              hipStream_t stream) {
  const float* x       = (const float*)d_in[0];
  const float* f_w1    = (const float*)d_in[1];
  const float* f_b1    = (const float*)d_in[2];
  const float* f_w2    = (const float*)d_in[3];
  const float* f_b2    = (const float*)d_in[4];
  const float* f_wp    = (const float*)d_in[5];
  const float* f_bp    = (const float*)d_in[6];
  const float* f_wg    = (const float*)d_in[7];
  const float* f_bg    = (const float*)d_in[8];
  const float* f_ws    = (const float*)d_in[9];
  const float* f_bs    = (const float*)d_in[10];
  const float* f_gamma = (const float*)d_in[11];
  const float* f_beta  = (const float*)d_in[12];
  const float* g_w1    = (const float*)d_in[13];
  const float* g_b1    = (const float*)d_in[14];
  const float* g_w2    = (const float*)d_in[15];
  const float* g_b2    = (const float*)d_in[16];
  const float* g_wp    = (const float*)d_in[17];
  const float* g_bp    = (const float*)d_in[18];
  const float* g_wg    = (const float*)d_in[19];
  const float* g_bg    = (const float*)d_in[20];
  const float* g_gamma = (const float*)d_in[21];
  const float* g_beta  = (const float*)d_in[22];
  const float* p_w     = (const float*)d_in[23];
  const float* p_b     = (const float*)d_in[24];

  float* out_sel = (float*)d_out;                  // [16384, 256]
  float* out_w   = out_sel + (size_t)M_TOT * D_N;  // [16384, 32]
  s16x8* pbw     = (s16x8*)d_ws;                   // 8 MB packed bf16 Wp'/Wg'
  float* pbias   = (float*)((char*)d_ws + (size_t)2 * 32 * 8192 * 16);  // 64 KB

  pack_wprime<<<512, 256, 0, stream>>>(f_w2, f_wp, f_wg, pbw);
  pack_bias<<<64, 256, 0, stream>>>(f_b2, f_wp, f_wg, f_bp, f_bg, pbias);
  vsn_weights<<<256, 64, 0, stream>>>(x, g_w1, g_b1, g_w2, g_b2, g_wp, g_bp,
                                      g_wg, g_bg, g_gamma, g_beta, p_w, p_b,
                                      out_w);
  vsn_main<<<256, 512, 0, stream>>>(x, f_w1, f_b1, f_ws, f_bs, f_gamma,
                                    f_beta, out_w, (const s16x8*)d_ws, pbias,
                                    out_sel);
}